// Round 17
// baseline (167.742 us; speedup 1.0000x reference)
//
#include <hip/hip_runtime.h>
#include <stdint.h>

// Problem constants (MultiHeadSelfAttention: B=4, T=2048, C=1024, H=16, D=64)
#define B_ 4
#define T_ 2048
#define C_ 1024
#define H_ 16
#define D_ 64
#define CK 1024  // K of both GEMMs (compile-time)

typedef __attribute__((ext_vector_type(8))) short bf8;
typedef __attribute__((ext_vector_type(4))) float f4;

__device__ __forceinline__ ushort f2bf(float f) {
  union { float f; uint32_t u; } c; c.f = f;
  uint32_t u = c.u;
  uint32_t r = (u + 0x7fffu + ((u >> 16) & 1u)) >> 16;  // RNE
  return (ushort)r;
}

__device__ __forceinline__ uint32_t cvtpk(float a, float b) {
  uint32_t r;
  asm("v_cvt_pk_bf16_f32 %0, %1, %2" : "=v"(r) : "v"(a), "v"(b));
  return r;
}

// ---------------------------------------------------------------- merged cast f32->bf16
__global__ __launch_bounds__(256) void cast_all(const float* __restrict__ x,
                                                const float* __restrict__ w0,
                                                const float* __restrict__ w1,
                                                const float* __restrict__ w2,
                                                const float* __restrict__ w3,
                                                ushort* __restrict__ xo,
                                                ushort* __restrict__ o0,
                                                ushort* __restrict__ o1,
                                                ushort* __restrict__ o2,
                                                ushort* __restrict__ o3) {
  int bid = blockIdx.x;
  const float* in;
  ushort* out;
  int lb;
  if (bid < 8192) {
    in = x; out = xo; lb = bid;
  } else {
    int wsel = (bid - 8192) >> 10;
    lb = (bid - 8192) & 1023;
    switch (wsel) {
      case 0: in = w0; out = o0; break;
      case 1: in = w1; out = o1; break;
      case 2: in = w2; out = o2; break;
      default: in = w3; out = o3; break;
    }
  }
  int i = (lb * 256 + threadIdx.x) * 4;
  float4 v = *(const float4*)(in + i);
  ushort4 o;
  o.x = f2bf(v.x); o.y = f2bf(v.y); o.z = f2bf(v.z); o.w = f2bf(v.w);
  *(ushort4*)(out + i) = o;
}

// ---------------------------------------------------------------- 128x384 QKV GEMM
// LDS-BW-bound fix: per-wave 64x96 output (acc[4][6]) cuts LDS bytes/MAC
// 0.064 -> 0.051.  512 thr = 8 waves (2M x 4N).  BK=64; LDS 128 KB dbuf
// (A 2x16KB, B 2x48KB).  Grid 64x8 = 512 = exactly 2 full rounds.
// 2 phases/K-step (3 B-subtiles each); FIFO-derived vmcnt(8) at both phases
// (P0 stages A+B012 = 5 loads, P1 stages B345 = 3).  Swizzle identical to gemm8
// (row&7 == lo&7 preserved: 96,16 = 0 mod 8).  Epilogue: per-16-col group proj
// select (384-tiles straddle the 1024 Q/K/V boundaries; 16-col groups never do).
__global__ __launch_bounds__(512, 2) void gemm384(const ushort* __restrict__ A,
                                                  const ushort* __restrict__ W,
                                                  const float* __restrict__ b0,
                                                  const float* __restrict__ b1,
                                                  const float* __restrict__ b2,
                                                  ushort* __restrict__ outp,
                                                  float qsc) {
  extern __shared__ ushort smem[];       // sA[2][8192] | sB[2][24576]
  ushort* sA = smem;
  ushort* sB = smem + 16384;

  const int tid = threadIdx.x;
  const int w = tid >> 6, l = tid & 63, lo = l & 15, hi = l >> 4;
  const int wm = w >> 2, wn = w & 3;

  const int i = blockIdx.x;
  const int m0 = ((i & 7) * 8 + ((i >> 3) & 7)) * 128;
  const int n0 = (i >> 6) * 384;

  // staging geometry
  const int rl = tid >> 3, c7 = tid & 7;
  const int scol = (c7 ^ (rl & 7)) * 8;             // pre-swizzled source col
  const ushort* Asrc = A + (size_t)(m0 + rl) * CK + scol;
  const ushort* Bsrc = W + (size_t)(n0 + rl) * CK + scol;

  // fragment-read swizzles
  const int sw0 = (hi ^ (lo & 7)) * 8;        // ks=0
  const int sw1 = ((4 + hi) ^ (lo & 7)) * 8;  // ks=1
  const int arow = wm * 64 + lo;
  const int brow = wn * 96 + lo;

  f4 acc[4][6];
#pragma unroll
  for (int f = 0; f < 4; ++f)
#pragma unroll
    for (int g = 0; g < 6; ++g) acc[f][g] = (f4){0.f, 0.f, 0.f, 0.f};

#define GL(src, dst) __builtin_amdgcn_global_load_lds(                                   \
      (const __attribute__((address_space(1))) void*)(src),                              \
      (__attribute__((address_space(3))) void*)(dst), 16, 0, 0)
#define STG_A(nb, kn) {                                                                  \
    GL(Asrc + (kn),                    &sA[(nb)*8192 + tid*8]);                          \
    GL(Asrc + (kn) + (size_t)64 * CK,  &sA[(nb)*8192 + 4096 + tid*8]); }
#define STG_B3(nb, h, kn) {                                                              \
    GL(Bsrc + (kn) + (size_t)(((h)*3 + 0) * 64) * CK, &sB[(nb)*24576 + ((h)*3 + 0)*4096 + tid*8]); \
    GL(Bsrc + (kn) + (size_t)(((h)*3 + 1) * 64) * CK, &sB[(nb)*24576 + ((h)*3 + 1)*4096 + tid*8]); \
    GL(Bsrc + (kn) + (size_t)(((h)*3 + 2) * 64) * CK, &sB[(nb)*24576 + ((h)*3 + 2)*4096 + tid*8]); }
#define VMC(s)  asm volatile("s_waitcnt vmcnt(" s ")" ::: "memory")
#define PH_BAR  { __builtin_amdgcn_s_barrier(); asm volatile("" ::: "memory"); }
#define LDA(cb) {                                                                        \
  _Pragma("unroll")                                                                      \
  for (int f = 0; f < 4; ++f) {                                                          \
    af[f][0] = *(const bf8*)&sA[(cb)*8192 + (arow + f*16)*64 + sw0];                     \
    af[f][1] = *(const bf8*)&sA[(cb)*8192 + (arow + f*16)*64 + sw1]; } }
#define LDB3(cb, dst, h) {                                                               \
  _Pragma("unroll")                                                                      \
  for (int g = 0; g < 3; ++g) {                                                          \
    dst[g][0] = *(const bf8*)&sB[(cb)*24576 + (brow + ((h)*3 + g)*16)*64 + sw0];         \
    dst[g][1] = *(const bf8*)&sB[(cb)*24576 + (brow + ((h)*3 + g)*16)*64 + sw1]; } }
#define MM24(h, bfr) {                                                                   \
  __builtin_amdgcn_s_setprio(1);                                                         \
  _Pragma("unroll")                                                                      \
  for (int f = 0; f < 4; ++f)                                                            \
    _Pragma("unroll")                                                                    \
    for (int g = 0; g < 3; ++g) {                                                        \
      acc[f][(h)*3+g] = __builtin_amdgcn_mfma_f32_16x16x32_bf16(af[f][0], bfr[g][0], acc[f][(h)*3+g], 0, 0, 0); \
      acc[f][(h)*3+g] = __builtin_amdgcn_mfma_f32_16x16x32_bf16(af[f][1], bfr[g][1], acc[f][(h)*3+g], 0, 0, 0); } \
  __builtin_amdgcn_s_setprio(0); }

  bf8 af[4][2], bA[3][2], bB[3][2];

  // prologue: fully stage buf0 at k=0 (8 loads)
  STG_A(0, 0); STG_B3(0, 0, 0); STG_B3(0, 1, 0);
  VMC("0"); PH_BAR;
  int cur = 0;

  for (int t = 0; t < (CK / 64) - 1; ++t) {  // 15 staged K-steps
    const int nb = cur ^ 1;
    const int kn = (t + 1) * 64;
    // P0: A frags + B subtiles 0-2; stage next A + B0-2; vmcnt(8) drains t-1's P0
    LDA(cur); LDB3(cur, bA, 0);
    STG_A(nb, kn); STG_B3(nb, 0, kn);
    VMC("8"); PH_BAR;
    MM24(0, bA); PH_BAR;
    // P1: B subtiles 3-5; stage next B3-5; vmcnt(8) drains t-1's P1
    LDB3(cur, bB, 1);
    STG_B3(nb, 1, kn);
    VMC("8"); PH_BAR;
    MM24(1, bB); PH_BAR;
    cur = nb;
  }
  // final K-step (fully staged; drain once, compute)
  VMC("0"); PH_BAR;
  LDA(cur); LDB3(cur, bA, 0); MM24(0, bA);
  LDB3(cur, bB, 1);           MM24(1, bB);
#undef GL
#undef STG_A
#undef STG_B3
#undef VMC
#undef PH_BAR
#undef LDA
#undef LDB3
#undef MM24

  // Epilogue (fused QKV only).  proj selected per 16-col group (wave-uniform).
#pragma unroll
  for (int f = 0; f < 4; ++f)
#pragma unroll
    for (int gn = 0; gn < 6; ++gn) {
      int n = n0 + wn * 96 + gn * 16 + lo;
      int proj = n >> 10;
      int nl = n & 1023;
      int h = nl >> 6, d = nl & 63;
      if (proj < 2) {
        const float* bp = (proj == 0) ? b0 : b1;
        const float os = (proj == 0) ? qsc : 1.0f;
        ushort* O = outp + (size_t)proj * (8u << 20);
        float bv = bp[nl];
#pragma unroll
        for (int j = 0; j < 4; ++j) {
          int m = m0 + wm * 64 + f * 16 + hi * 4 + j;
          int b = m >> 11, t = m & 2047;
          O[(size_t)((b << 4) + h) * (T_ * D_) + t * D_ + d] = f2bf((acc[f][gn][j] + bv) * os);
        }
      } else {
        // V: write DIRECTLY TRANSPOSED [bh][d][t] (4 consecutive t -> ushort4)
        ushort* O = outp + (size_t)2 * (8u << 20);
        float bv = b2[nl];
        int mb = m0 + wm * 64 + f * 16 + hi * 4;  // 4-aligned; never straddles b
        int b = mb >> 11, t = mb & 2047;
        ushort4 pk;
        pk.x = f2bf(acc[f][gn][0] + bv);
        pk.y = f2bf(acc[f][gn][1] + bv);
        pk.z = f2bf(acc[f][gn][2] + bv);
        pk.w = f2bf(acc[f][gn][3] + bv);
        *(ushort4*)&O[((size_t)((b << 4) + h) * D_ + d) * T_ + t] = pk;
      }
    }
}

// ---------------------------------------------------------------- 8-wave 128x256 GEMM
// (byte-identical to R16-passing version; used for the final projection, mode 0)
__global__ __launch_bounds__(512, 2) void gemm8(const ushort* __restrict__ A,
                                                const ushort* __restrict__ W,
                                                const float* __restrict__ b0,
                                                const float* __restrict__ b1,
                                                const float* __restrict__ b2,
                                                void* __restrict__ outp,
                                                int mode, float qsc) {
  extern __shared__ ushort smem[];       // sA[2][8192] | sB[2][16384]
  ushort* sA = smem;
  ushort* sB = smem + 16384;

  const int tid = threadIdx.x;
  const int w = tid >> 6, l = tid & 63, lo = l & 15, hi = l >> 4;
  const int wm = w >> 2, wn = w & 3;

  const int i = blockIdx.x;
  const int m0 = ((i & 7) * 8 + ((i >> 3) & 7)) * 128;
  const int n0 = (i >> 6) * 256;

  const int rl = tid >> 3, c7 = tid & 7;
  const int scol = (c7 ^ (rl & 7)) * 8;
  const ushort* Asrc = A + (size_t)(m0 + rl) * CK + scol;
  const int Brow0 = ((rl >> 5) * 64) + (rl & 31);
  const ushort* Bsrc = W + (size_t)(n0 + Brow0) * CK + scol;
  const int Bdst0 = Brow0 * 64 + c7 * 8;

  const int sw0 = (hi ^ (lo & 7)) * 8;
  const int sw1 = ((4 + hi) ^ (lo & 7)) * 8;
  const int arow = wm * 64 + lo;
  const int brow = wn * 64 + lo;

  f4 acc[4][4];
#pragma unroll
  for (int f = 0; f < 4; ++f)
#pragma unroll
    for (int g = 0; g < 4; ++g) acc[f][g] = (f4){0.f, 0.f, 0.f, 0.f};

#define GL(src, dst) __builtin_amdgcn_global_load_lds(                                   \
      (const __attribute__((address_space(1))) void*)(src),                              \
      (__attribute__((address_space(3))) void*)(dst), 16, 0, 0)
#define STG_A(nb, kn) {                                                                  \
    GL(Asrc + (kn),                    &sA[(nb)*8192 + tid*8]);                          \
    GL(Asrc + (kn) + (size_t)64 * CK,  &sA[(nb)*8192 + 4096 + tid*8]); }
#define STG_B(nb, h, kn) {                                                               \
    GL(Bsrc + (kn) + (size_t)((h)*32) * CK,        &sB[(nb)*16384 + (h)*2048 + Bdst0]);           \
    GL(Bsrc + (kn) + (size_t)((h)*32 + 128) * CK,  &sB[(nb)*16384 + (h)*2048 + 8192 + Bdst0]); }
#define VMC(s)  asm volatile("s_waitcnt vmcnt(" s ")" ::: "memory")
#define PH_BAR  { __builtin_amdgcn_s_barrier(); asm volatile("" ::: "memory"); }
#define LDA_H(cb, hh) {                                                                  \
  _Pragma("unroll")                                                                      \
  for (int f = (hh)*2; f < (hh)*2 + 2; ++f) {                                            \
    af[f][0] = *(const bf8*)&sA[(cb)*8192 + (arow + f*16)*64 + sw0];                     \
    af[f][1] = *(const bf8*)&sA[(cb)*8192 + (arow + f*16)*64 + sw1]; } }
#define LDB(cb, dst, h) {                                                                \
  _Pragma("unroll")                                                                      \
  for (int g = 0; g < 2; ++g) {                                                          \
    dst[g][0] = *(const bf8*)&sB[(cb)*16384 + (brow + (h)*32 + g*16)*64 + sw0];          \
    dst[g][1] = *(const bf8*)&sB[(cb)*16384 + (brow + (h)*32 + g*16)*64 + sw1]; } }
#define MM8(fo, go, bfr) {                                                               \
  __builtin_amdgcn_s_setprio(1);                                                         \
  _Pragma("unroll")                                                                      \
  for (int f = (fo); f < (fo) + 2; ++f)                                                  \
    _Pragma("unroll")                                                                    \
    for (int g = 0; g < 2; ++g) {                                                        \
      acc[f][(go)+g] = __builtin_amdgcn_mfma_f32_16x16x32_bf16(af[f][0], bfr[g][0], acc[f][(go)+g], 0, 0, 0); \
      acc[f][(go)+g] = __builtin_amdgcn_mfma_f32_16x16x32_bf16(af[f][1], bfr[g][1], acc[f][(go)+g], 0, 0, 0); } \
  __builtin_amdgcn_s_setprio(0); }

  bf8 af[4][2], bA[2][2], bB[2][2];

  STG_A(0, 0); STG_B(0, 0, 0); STG_B(0, 1, 0);
  VMC("0"); PH_BAR;
  int cur = 0;

  for (int t = 0; t < (CK / 64) - 1; ++t) {
    const int nb = cur ^ 1;
    const int kn = (t + 1) * 64;
    LDA_H(cur, 0); LDB(cur, bA, 0);
    STG_A(nb, kn);
    VMC("4"); PH_BAR;
    MM8(0, 0, bA); PH_BAR;
    LDA_H(cur, 1);
    STG_B(nb, 0, kn);
    PH_BAR;
    MM8(2, 0, bA); PH_BAR;
    LDB(cur, bB, 1);
    STG_B(nb, 1, kn);
    VMC("6"); PH_BAR;
    MM8(0, 2, bB); PH_BAR;
    MM8(2, 2, bB); PH_BAR;
    cur = nb;
  }
  VMC("0"); PH_BAR;
  LDA_H(cur, 0); LDB(cur, bA, 0); MM8(0, 0, bA);
  LDA_H(cur, 1);                  MM8(2, 0, bA);
  LDB(cur, bB, 1);                MM8(0, 2, bB);
                                  MM8(2, 2, bB);
#undef GL
#undef STG_A
#undef STG_B
#undef VMC
#undef PH_BAR
#undef LDA_H
#undef LDB
#undef MM8

  if (mode == 0) {
    float* O = (float*)outp;
#pragma unroll
    for (int f = 0; f < 4; ++f)
#pragma unroll
      for (int gn = 0; gn < 4; ++gn) {
        int n = n0 + wn * 64 + gn * 16 + lo;
        float bv = b0[n];
#pragma unroll
        for (int j = 0; j < 4; ++j) {
          int m = m0 + wm * 64 + f * 16 + hi * 4 + j;
          O[(size_t)m * C_ + n] = acc[f][gn][j] + bv;
        }
      }
  } else {
    const int proj = n0 >> 10;
    if (proj < 2) {
      const float* bp = (proj == 0) ? b0 : b1;
      const float os = (proj == 0) ? qsc : 1.0f;
      ushort* O = (ushort*)outp + (size_t)proj * (8u << 20);
#pragma unroll
      for (int f = 0; f < 4; ++f)
#pragma unroll
        for (int gn = 0; gn < 4; ++gn) {
          int n = n0 + wn * 64 + gn * 16 + lo;
          int nl = n & 1023;
          int h = nl >> 6, d = nl & 63;
          float bv = bp[nl];
#pragma unroll
          for (int j = 0; j < 4; ++j) {
            int m = m0 + wm * 64 + f * 16 + hi * 4 + j;
            int b = m >> 11, t = m & 2047;
            O[(size_t)((b << 4) + h) * (T_ * D_) + t * D_ + d] = f2bf((acc[f][gn][j] + bv) * os);
          }
        }
    } else {
      ushort* O = (ushort*)outp + (size_t)2 * (8u << 20);
#pragma unroll
      for (int f = 0; f < 4; ++f)
#pragma unroll
        for (int gn = 0; gn < 4; ++gn) {
          int n = n0 + wn * 64 + gn * 16 + lo;
          int nl = n & 1023;
          int h = nl >> 6, d = nl & 63;
          float bv = b2[nl];
          int mb = m0 + wm * 64 + f * 16 + hi * 4;
          int b = mb >> 11, t = mb & 2047;
          ushort4 pk;
          pk.x = f2bf(acc[f][gn][0] + bv);
          pk.y = f2bf(acc[f][gn][1] + bv);
          pk.z = f2bf(acc[f][gn][2] + bv);
          pk.w = f2bf(acc[f][gn][3] + bv);
          *(ushort4*)&O[((size_t)((b << 4) + h) * D_ + d) * T_ + t] = pk;
        }
    }
  }
}

// ---------------------------------------------------------------- flash attention
// (byte-identical to the R13/R15/R16-passing version)
__global__ __launch_bounds__(256, 4) void attn_kernel(const ushort* __restrict__ Q,
                                                      const ushort* __restrict__ Kg,
                                                      const ushort* __restrict__ VT,
                                                      ushort* __restrict__ O) {
  __shared__ ushort Ks[2][64 * 64];
  __shared__ ushort Vs[2][64 * 64];

  const int tid = threadIdx.x;
  const int w = tid >> 6, l = tid & 63, lo = l & 15, hi = l >> 4;
  const int linear = blockIdx.y * 16 + blockIdx.x;
  const int bh = (linear & 7) * 8 + ((linear >> 3) & 7);
  const int q0 = (linear >> 6) * 128 + w * 32;
  const ushort* Qb  = Q  + (size_t)bh * T_ * D_;
  const ushort* Kb  = Kg + (size_t)bh * T_ * D_;
  const ushort* VTb = VT + (size_t)bh * D_ * T_;

  bf8 qf[2][2];
#pragma unroll
  for (int qs = 0; qs < 2; ++qs)
#pragma unroll
    for (int c = 0; c < 2; ++c)
      qf[qs][c] = *(const bf8*)&Qb[(q0 + qs * 16 + lo) * D_ + c * 32 + hi * 8];

  f4 o[2][4], accL[2];
#pragma unroll
  for (int qs = 0; qs < 2; ++qs) {
    accL[qs] = (f4){0.f, 0.f, 0.f, 0.f};
#pragma unroll
    for (int dt = 0; dt < 4; ++dt) o[qs][dt] = (f4){0.f, 0.f, 0.f, 0.f};
  }
  const short ONE = 0x3F80;  // bf16 1.0
  const bf8 ones = (bf8){ONE, ONE, ONE, ONE, ONE, ONE, ONE, ONE};

  const int rowA  = tid >> 3;
  const int colsw = ((tid & 7) ^ (rowA & 7)) * 8;
  const int permA = ((rowA >> 2) & 3) * 8 + ((rowA >> 4) & 1) * 4 + (rowA & 3);
  const ushort* Ksrc0 = Kb  + (size_t)permA * D_ + colsw;
  const ushort* Ksrc1 = Kb  + (size_t)(32 + permA) * D_ + colsw;
  const ushort* Vsrc0 = VTb + (size_t)rowA * T_ + colsw;
  const ushort* Vsrc1 = VTb + (size_t)(rowA + 32) * T_ + colsw;

  const int swz = (lo & 7) << 3;
  const int NT = T_ / 64;

#define STAGE(b, kvo)                                                                              \
  {                                                                                                \
    __builtin_amdgcn_global_load_lds((const __attribute__((address_space(1))) void*)(Ksrc0 + (size_t)(kvo) * D_), \
                                     (__attribute__((address_space(3))) void*)&Ks[b][tid * 8], 16, 0, 0);          \
    __builtin_amdgcn_global_load_lds((const __attribute__((address_space(1))) void*)(Ksrc1 + (size_t)(kvo) * D_), \
                                     (__attribute__((address_space(3))) void*)&Ks[b][2048 + tid * 8], 16, 0, 0);   \
    __builtin_amdgcn_global_load_lds((const __attribute__((address_space(1))) void*)(Vsrc0 + (kvo)),               \
                                     (__attribute__((address_space(3))) void*)&Vs[b][tid * 8], 16, 0, 0);          \
    __builtin_amdgcn_global_load_lds((const __attribute__((address_space(1))) void*)(Vsrc1 + (kvo)),               \
                                     (__attribute__((address_space(3))) void*)&Vs[b][2048 + tid * 8], 16, 0, 0);   \
  }

  STAGE(0, 0);
  __syncthreads();
  int cur = 0;

  for (int t = 0; t < NT; ++t) {
    if (t + 1 < NT) STAGE(cur ^ 1, (t + 1) * 64);

    const ushort* Kc = &Ks[cur][0];
    const ushort* Vc = &Vs[cur][0];

    bf8 kf[4][2], vf[4][2];
#pragma unroll
    for (int n = 0; n < 4; ++n) {
      kf[n][0] = *(const bf8*)&Kc[(n * 16 + lo) * 64 + ((hi * 8) ^ swz)];
      kf[n][1] = *(const bf8*)&Kc[(n * 16 + lo) * 64 + ((32 + hi * 8) ^ swz)];
    }
#pragma unroll
    for (int dt = 0; dt < 4; ++dt) {
      vf[dt][0] = *(const bf8*)&Vc[(dt * 16 + lo) * 64 + ((hi * 8) ^ swz)];
      vf[dt][1] = *(const bf8*)&Vc[(dt * 16 + lo) * 64 + ((32 + hi * 8) ^ swz)];
    }

#pragma unroll
    for (int qs = 0; qs < 2; ++qs) {
      f4 z[4];
#pragma unroll
      for (int n = 0; n < 4; ++n) {
        f4 zz = (f4){0.f, 0.f, 0.f, 0.f};
        zz = __builtin_amdgcn_mfma_f32_16x16x32_bf16(kf[n][0], qf[qs][0], zz, 0, 0, 0);
        zz = __builtin_amdgcn_mfma_f32_16x16x32_bf16(kf[n][1], qf[qs][1], zz, 0, 0, 0);
        z[n] = zz;
      }

      uint32_t pd[8];
#pragma unroll
      for (int n = 0; n < 4; ++n) {
        float e0 = __builtin_amdgcn_exp2f(z[n][0]);
        float e1 = __builtin_amdgcn_exp2f(z[n][1]);
        float e2 = __builtin_amdgcn_exp2f(z[n][2]);
        float e3 = __builtin_amdgcn_exp2f(z[n][3]);
        pd[n * 2 + 0] = cvtpk(e0, e1);
        pd[n * 2 + 1] = cvtpk(e2, e3);
      }
      union U8 { uint32_t u[4]; bf8 v; } u0, u1;
      u0.u[0] = pd[0]; u0.u[1] = pd[1]; u0.u[2] = pd[2]; u0.u[3] = pd[3];
      u1.u[0] = pd[4]; u1.u[1] = pd[5]; u1.u[2] = pd[6]; u1.u[3] = pd[7];

      accL[qs] = __builtin_amdgcn_mfma_f32_16x16x32_bf16(u0.v, ones, accL[qs], 0, 0, 0);
      accL[qs] = __builtin_amdgcn_mfma_f32_16x16x32_bf16(u1.v, ones, accL[qs], 0, 0, 0);

#pragma unroll
      for (int dt = 0; dt < 4; ++dt) {
        o[qs][dt] = __builtin_amdgcn_mfma_f32_16x16x32_bf16(u0.v, vf[dt][0], o[qs][dt], 0, 0, 0);
        o[qs][dt] = __builtin_amdgcn_mfma_f32_16x16x32_bf16(u1.v, vf[dt][1], o[qs][dt], 0, 0, 0);
      }
    }

    __syncthreads();
    cur ^= 1;
  }
#undef STAGE

  const int b = bh >> 4, h = bh & 15;
#pragma unroll
  for (int qs = 0; qs < 2; ++qs)
#pragma unroll
    for (int j = 0; j < 4; ++j) {
      float invL = 1.0f / accL[qs][j];
      int q = q0 + qs * 16 + hi * 4 + j;
#pragma unroll
      for (int dt = 0; dt < 4; ++dt)
        O[(size_t)(b * T_ + q) * C_ + h * D_ + dt * 16 + lo] = f2bf(o[qs][dt][j] * invL);
    }
}

// ---------------------------------------------------------------- launch
extern "C" void kernel_launch(void* const* d_in, const int* in_sizes, int n_in,
                              void* d_out, int out_size, void* d_ws, size_t ws_size,
                              hipStream_t stream) {
  const float* x  = (const float*)d_in[0];
  // d_in[1] = mask: unused by the reference
  const float* qw = (const float*)d_in[2];
  const float* qb = (const float*)d_in[3];
  const float* kw = (const float*)d_in[4];
  const float* kb = (const float*)d_in[5];
  const float* vw = (const float*)d_in[6];
  const float* vb = (const float*)d_in[7];
  const float* ow = (const float*)d_in[8];
  const float* ob = (const float*)d_in[9];
  float* out = (float*)d_out;

  // workspace layout (88 MB). Q,K: [bh][t][d]; VT: [bh][d][t].
  char* ws = (char*)d_ws;
  ushort* xbf   = (ushort*)ws;                       // 16 MB
  ushort* qwbf  = (ushort*)(ws + (16u << 20));       // 2 MB each, contiguous (QKV stacked W)
  ushort* kwbf  = qwbf + (1u << 20);
  ushort* vwbf  = kwbf + (1u << 20);
  ushort* owbf  = vwbf + (1u << 20);
  ushort* Qws   = (ushort*)(ws + (24u << 20));       // Q @24MB, K @40MB, VT @56MB
  ushort* VTws  = (ushort*)(ws + (56u << 20));
  ushort* attnw = (ushort*)(ws + (72u << 20));

  hipFuncSetAttribute((const void*)gemm384, hipFuncAttributeMaxDynamicSharedMemorySize, 131072);
  hipFuncSetAttribute((const void*)gemm8, hipFuncAttributeMaxDynamicSharedMemorySize, 98304);

  // merged cast: x (8192 blocks) + 4 weights (4096 blocks)
  cast_all<<<12288, 256, 0, stream>>>(x, qw, kw, vw, ow, xbf, qwbf, kwbf, vwbf, owbf);

  const float QSC = 0.125f * 1.44269504f;  // 1/sqrt(D) * log2(e), folded into Q
  // fused QKV projection: N=3072 -> 8 n-tiles x 64 m-tiles = 512 blocks (2 full rounds)
  gemm384<<<512, 512, 131072, stream>>>(xbf, qwbf, qb, kb, vb, Qws, QSC);

  attn_kernel<<<dim3(T_ / 128, B_ * H_), 256, 0, stream>>>(Qws, Qws + (size_t)(8u << 20), VTws, attnw);

  // final projection: N=1024 -> 4 n-tiles x 64 m-tiles = 256 blocks (1 full round)
  gemm8<<<256, 512, 98304, stream>>>(attnw, owbf, ob, nullptr, nullptr, out, 0, 1.0f);
}

// Round 18
// 162.376 us; speedup vs baseline: 1.0330x; 1.0330x over previous
//
#include <hip/hip_runtime.h>
#include <stdint.h>

// Problem constants (MultiHeadSelfAttention: B=4, T=2048, C=1024, H=16, D=64)
#define B_ 4
#define T_ 2048
#define C_ 1024
#define H_ 16
#define D_ 64
#define CK 1024  // K of both GEMMs (compile-time)

typedef __attribute__((ext_vector_type(8))) short bf8;
typedef __attribute__((ext_vector_type(4))) float f4;

__device__ __forceinline__ ushort f2bf(float f) {
  union { float f; uint32_t u; } c; c.f = f;
  uint32_t u = c.u;
  uint32_t r = (u + 0x7fffu + ((u >> 16) & 1u)) >> 16;  // RNE
  return (ushort)r;
}

__device__ __forceinline__ uint32_t cvtpk(float a, float b) {
  uint32_t r;
  asm("v_cvt_pk_bf16_f32 %0, %1, %2" : "=v"(r) : "v"(a), "v"(b));
  return r;
}

// ---------------------------------------------------------------- merged cast f32->bf16
// blocks [0,8192): x (8M elems).  blocks [8192,12288): weights (4 x 1M elems).
__global__ __launch_bounds__(256) void cast_all(const float* __restrict__ x,
                                                const float* __restrict__ w0,
                                                const float* __restrict__ w1,
                                                const float* __restrict__ w2,
                                                const float* __restrict__ w3,
                                                ushort* __restrict__ xo,
                                                ushort* __restrict__ o0,
                                                ushort* __restrict__ o1,
                                                ushort* __restrict__ o2,
                                                ushort* __restrict__ o3) {
  int bid = blockIdx.x;
  const float* in;
  ushort* out;
  int lb;
  if (bid < 8192) {
    in = x; out = xo; lb = bid;
  } else {
    int wsel = (bid - 8192) >> 10;
    lb = (bid - 8192) & 1023;
    switch (wsel) {
      case 0: in = w0; out = o0; break;
      case 1: in = w1; out = o1; break;
      case 2: in = w2; out = o2; break;
      default: in = w3; out = o3; break;
    }
  }
  int i = (lb * 256 + threadIdx.x) * 4;
  float4 v = *(const float4*)(in + i);
  ushort4 o;
  o.x = f2bf(v.x); o.y = f2bf(v.y); o.z = f2bf(v.z); o.w = f2bf(v.w);
  *(ushort4*)(out + i) = o;
}

// ---------------------------------------------------------------- 8-wave 128x256 GEMM
// R15 tile/mapping, 4-phase schedule (R16-passing version, byte-identical).
__global__ __launch_bounds__(512, 2) void gemm8(const ushort* __restrict__ A,
                                                const ushort* __restrict__ W,
                                                const float* __restrict__ b0,
                                                const float* __restrict__ b1,
                                                const float* __restrict__ b2,
                                                void* __restrict__ outp,
                                                int mode, float qsc) {
  extern __shared__ ushort smem[];       // sA[2][8192] | sB[2][16384]
  ushort* sA = smem;
  ushort* sB = smem + 16384;

  const int tid = threadIdx.x;
  const int w = tid >> 6, l = tid & 63, lo = l & 15, hi = l >> 4;
  const int wm = w >> 2, wn = w & 3;

  const int i = blockIdx.x;
  const int m0 = ((i & 7) * 8 + ((i >> 3) & 7)) * 128;
  const int n0 = (i >> 6) * 256;

  // staging geometry
  const int rl = tid >> 3, c7 = tid & 7;
  const int scol = (c7 ^ (rl & 7)) * 8;             // pre-swizzled source col
  const ushort* Asrc = A + (size_t)(m0 + rl) * CK + scol;
  const int Brow0 = ((rl >> 5) * 64) + (rl & 31);   // {0..31} u {64..95}
  const ushort* Bsrc = W + (size_t)(n0 + Brow0) * CK + scol;
  const int Bdst0 = Brow0 * 64 + c7 * 8;

  // fragment-read swizzles
  const int sw0 = (hi ^ (lo & 7)) * 8;        // ks=0
  const int sw1 = ((4 + hi) ^ (lo & 7)) * 8;  // ks=1
  const int arow = wm * 64 + lo;
  const int brow = wn * 64 + lo;

  f4 acc[4][4];
#pragma unroll
  for (int f = 0; f < 4; ++f)
#pragma unroll
    for (int g = 0; g < 4; ++g) acc[f][g] = (f4){0.f, 0.f, 0.f, 0.f};

#define GL(src, dst) __builtin_amdgcn_global_load_lds(                                   \
      (const __attribute__((address_space(1))) void*)(src),                              \
      (__attribute__((address_space(3))) void*)(dst), 16, 0, 0)
#define STG_A(nb, kn) {                                                                  \
    GL(Asrc + (kn),                    &sA[(nb)*8192 + tid*8]);                          \
    GL(Asrc + (kn) + (size_t)64 * CK,  &sA[(nb)*8192 + 4096 + tid*8]); }
#define STG_B(nb, h, kn) {                                                               \
    GL(Bsrc + (kn) + (size_t)((h)*32) * CK,        &sB[(nb)*16384 + (h)*2048 + Bdst0]);           \
    GL(Bsrc + (kn) + (size_t)((h)*32 + 128) * CK,  &sB[(nb)*16384 + (h)*2048 + 8192 + Bdst0]); }
#define VMC(s)  asm volatile("s_waitcnt vmcnt(" s ")" ::: "memory")
#define PH_BAR  { __builtin_amdgcn_s_barrier(); asm volatile("" ::: "memory"); }
#define LDA_H(cb, hh) {                                                                  \
  _Pragma("unroll")                                                                      \
  for (int f = (hh)*2; f < (hh)*2 + 2; ++f) {                                            \
    af[f][0] = *(const bf8*)&sA[(cb)*8192 + (arow + f*16)*64 + sw0];                     \
    af[f][1] = *(const bf8*)&sA[(cb)*8192 + (arow + f*16)*64 + sw1]; } }
#define LDB(cb, dst, h) {                                                                \
  _Pragma("unroll")                                                                      \
  for (int g = 0; g < 2; ++g) {                                                          \
    dst[g][0] = *(const bf8*)&sB[(cb)*16384 + (brow + (h)*32 + g*16)*64 + sw0];          \
    dst[g][1] = *(const bf8*)&sB[(cb)*16384 + (brow + (h)*32 + g*16)*64 + sw1]; } }
#define MM8(fo, go, bfr) {                                                               \
  __builtin_amdgcn_s_setprio(1);                                                         \
  _Pragma("unroll")                                                                      \
  for (int f = (fo); f < (fo) + 2; ++f)                                                  \
    _Pragma("unroll")                                                                    \
    for (int g = 0; g < 2; ++g) {                                                        \
      acc[f][(go)+g] = __builtin_amdgcn_mfma_f32_16x16x32_bf16(af[f][0], bfr[g][0], acc[f][(go)+g], 0, 0, 0); \
      acc[f][(go)+g] = __builtin_amdgcn_mfma_f32_16x16x32_bf16(af[f][1], bfr[g][1], acc[f][(go)+g], 0, 0, 0); } \
  __builtin_amdgcn_s_setprio(0); }

  bf8 af[4][2], bA[2][2], bB[2][2];

  // prologue: fully stage buf0 at k=0 (6 loads)
  STG_A(0, 0); STG_B(0, 0, 0); STG_B(0, 1, 0);
  VMC("0"); PH_BAR;
  int cur = 0;

  for (int t = 0; t < (CK / 64) - 1; ++t) {  // 15 staged K-steps
    const int nb = cur ^ 1;
    const int kn = (t + 1) * 64;
    // PA: A-half0 + B-half0 frags; stage next A; drain t-1's A+B0
    LDA_H(cur, 0); LDB(cur, bA, 0);
    STG_A(nb, kn);
    VMC("4"); PH_BAR;
    MM8(0, 0, bA); PH_BAR;
    // PB: A-half1 frags; stage next B0
    LDA_H(cur, 1);
    STG_B(nb, 0, kn);
    PH_BAR;
    MM8(2, 0, bA); PH_BAR;
    // PC: B-half1 frags; stage next B1; drain t-1's B1
    LDB(cur, bB, 1);
    STG_B(nb, 1, kn);
    VMC("6"); PH_BAR;
    MM8(0, 2, bB); PH_BAR;
    // PD: pure MFMA
    MM8(2, 2, bB); PH_BAR;
    cur = nb;
  }
  // final K-step (fully staged; drain once, compute)
  VMC("0"); PH_BAR;
  LDA_H(cur, 0); LDB(cur, bA, 0); MM8(0, 0, bA);
  LDA_H(cur, 1);                  MM8(2, 0, bA);
  LDB(cur, bB, 1);                MM8(0, 2, bB);
                                  MM8(2, 2, bB);
#undef GL
#undef STG_A
#undef STG_B
#undef VMC
#undef PH_BAR
#undef LDA_H
#undef LDB
#undef MM8

  // Epilogue. C/D layout: row = hi*4+j, col = lo.
  if (mode == 0) {
    float* O = (float*)outp;
#pragma unroll
    for (int f = 0; f < 4; ++f)
#pragma unroll
      for (int gn = 0; gn < 4; ++gn) {
        int n = n0 + wn * 64 + gn * 16 + lo;
        float bv = b0[n];
#pragma unroll
        for (int j = 0; j < 4; ++j) {
          int m = m0 + wm * 64 + f * 16 + hi * 4 + j;
          O[(size_t)m * C_ + n] = acc[f][gn][j] + bv;
        }
      }
  } else {
    const int proj = n0 >> 10;  // 256-tiles never straddle 1024 boundaries
    if (proj < 2) {
      // Q (scaled) / K: head-split [bh][t][d]
      const float* bp = (proj == 0) ? b0 : b1;
      const float os = (proj == 0) ? qsc : 1.0f;
      ushort* O = (ushort*)outp + (size_t)proj * (8u << 20);
#pragma unroll
      for (int f = 0; f < 4; ++f)
#pragma unroll
        for (int gn = 0; gn < 4; ++gn) {
          int n = n0 + wn * 64 + gn * 16 + lo;
          int nl = n & 1023;
          int h = nl >> 6, d = nl & 63;
          float bv = bp[nl];
#pragma unroll
          for (int j = 0; j < 4; ++j) {
            int m = m0 + wm * 64 + f * 16 + hi * 4 + j;
            int b = m >> 11, t = m & 2047;
            O[(size_t)((b << 4) + h) * (T_ * D_) + t * D_ + d] = f2bf((acc[f][gn][j] + bv) * os);
          }
        }
    } else {
      // V: write DIRECTLY TRANSPOSED [bh][d][t] (4 consecutive t -> ushort4)
      ushort* O = (ushort*)outp + (size_t)2 * (8u << 20);
#pragma unroll
      for (int f = 0; f < 4; ++f)
#pragma unroll
        for (int gn = 0; gn < 4; ++gn) {
          int n = n0 + wn * 64 + gn * 16 + lo;
          int nl = n & 1023;
          int h = nl >> 6, d = nl & 63;
          float bv = b2[nl];
          int mb = m0 + wm * 64 + f * 16 + hi * 4;  // 4-aligned; tile never straddles b
          int b = mb >> 11, t = mb & 2047;
          ushort4 pk;
          pk.x = f2bf(acc[f][gn][0] + bv);
          pk.y = f2bf(acc[f][gn][1] + bv);
          pk.z = f2bf(acc[f][gn][2] + bv);
          pk.w = f2bf(acc[f][gn][3] + bv);
          *(ushort4*)&O[((size_t)((b << 4) + h) * D_ + d) * T_ + t] = pk;
        }
    }
  }
}

// ---------------------------------------------------------------- flash attention
// (byte-identical to the R13/R15/R16-passing version)
__global__ __launch_bounds__(256, 4) void attn_kernel(const ushort* __restrict__ Q,
                                                      const ushort* __restrict__ Kg,
                                                      const ushort* __restrict__ VT,
                                                      ushort* __restrict__ O) {
  __shared__ ushort Ks[2][64 * 64];
  __shared__ ushort Vs[2][64 * 64];

  const int tid = threadIdx.x;
  const int w = tid >> 6, l = tid & 63, lo = l & 15, hi = l >> 4;
  const int linear = blockIdx.y * 16 + blockIdx.x;
  const int bh = (linear & 7) * 8 + ((linear >> 3) & 7);
  const int q0 = (linear >> 6) * 128 + w * 32;
  const ushort* Qb  = Q  + (size_t)bh * T_ * D_;
  const ushort* Kb  = Kg + (size_t)bh * T_ * D_;
  const ushort* VTb = VT + (size_t)bh * D_ * T_;

  bf8 qf[2][2];
#pragma unroll
  for (int qs = 0; qs < 2; ++qs)
#pragma unroll
    for (int c = 0; c < 2; ++c)
      qf[qs][c] = *(const bf8*)&Qb[(q0 + qs * 16 + lo) * D_ + c * 32 + hi * 8];

  f4 o[2][4], accL[2];
#pragma unroll
  for (int qs = 0; qs < 2; ++qs) {
    accL[qs] = (f4){0.f, 0.f, 0.f, 0.f};
#pragma unroll
    for (int dt = 0; dt < 4; ++dt) o[qs][dt] = (f4){0.f, 0.f, 0.f, 0.f};
  }
  const short ONE = 0x3F80;  // bf16 1.0
  const bf8 ones = (bf8){ONE, ONE, ONE, ONE, ONE, ONE, ONE, ONE};

  const int rowA  = tid >> 3;
  const int colsw = ((tid & 7) ^ (rowA & 7)) * 8;
  const int permA = ((rowA >> 2) & 3) * 8 + ((rowA >> 4) & 1) * 4 + (rowA & 3);
  const ushort* Ksrc0 = Kb  + (size_t)permA * D_ + colsw;
  const ushort* Ksrc1 = Kb  + (size_t)(32 + permA) * D_ + colsw;
  const ushort* Vsrc0 = VTb + (size_t)rowA * T_ + colsw;
  const ushort* Vsrc1 = VTb + (size_t)(rowA + 32) * T_ + colsw;

  const int swz = (lo & 7) << 3;
  const int NT = T_ / 64;

#define STAGE(b, kvo)                                                                              \
  {                                                                                                \
    __builtin_amdgcn_global_load_lds((const __attribute__((address_space(1))) void*)(Ksrc0 + (size_t)(kvo) * D_), \
                                     (__attribute__((address_space(3))) void*)&Ks[b][tid * 8], 16, 0, 0);          \
    __builtin_amdgcn_global_load_lds((const __attribute__((address_space(1))) void*)(Ksrc1 + (size_t)(kvo) * D_), \
                                     (__attribute__((address_space(3))) void*)&Ks[b][2048 + tid * 8], 16, 0, 0);   \
    __builtin_amdgcn_global_load_lds((const __attribute__((address_space(1))) void*)(Vsrc0 + (kvo)),               \
                                     (__attribute__((address_space(3))) void*)&Vs[b][tid * 8], 16, 0, 0);          \
    __builtin_amdgcn_global_load_lds((const __attribute__((address_space(1))) void*)(Vsrc1 + (kvo)),               \
                                     (__attribute__((address_space(3))) void*)&Vs[b][2048 + tid * 8], 16, 0, 0);   \
  }

  STAGE(0, 0);
  __syncthreads();
  int cur = 0;

  for (int t = 0; t < NT; ++t) {
    if (t + 1 < NT) STAGE(cur ^ 1, (t + 1) * 64);

    const ushort* Kc = &Ks[cur][0];
    const ushort* Vc = &Vs[cur][0];

    bf8 kf[4][2], vf[4][2];
#pragma unroll
    for (int n = 0; n < 4; ++n) {
      kf[n][0] = *(const bf8*)&Kc[(n * 16 + lo) * 64 + ((hi * 8) ^ swz)];
      kf[n][1] = *(const bf8*)&Kc[(n * 16 + lo) * 64 + ((32 + hi * 8) ^ swz)];
    }
#pragma unroll
    for (int dt = 0; dt < 4; ++dt) {
      vf[dt][0] = *(const bf8*)&Vc[(dt * 16 + lo) * 64 + ((hi * 8) ^ swz)];
      vf[dt][1] = *(const bf8*)&Vc[(dt * 16 + lo) * 64 + ((32 + hi * 8) ^ swz)];
    }

#pragma unroll
    for (int qs = 0; qs < 2; ++qs) {
      f4 z[4];
#pragma unroll
      for (int n = 0; n < 4; ++n) {
        f4 zz = (f4){0.f, 0.f, 0.f, 0.f};
        zz = __builtin_amdgcn_mfma_f32_16x16x32_bf16(kf[n][0], qf[qs][0], zz, 0, 0, 0);
        zz = __builtin_amdgcn_mfma_f32_16x16x32_bf16(kf[n][1], qf[qs][1], zz, 0, 0, 0);
        z[n] = zz;
      }

      uint32_t pd[8];
#pragma unroll
      for (int n = 0; n < 4; ++n) {
        float e0 = __builtin_amdgcn_exp2f(z[n][0]);
        float e1 = __builtin_amdgcn_exp2f(z[n][1]);
        float e2 = __builtin_amdgcn_exp2f(z[n][2]);
        float e3 = __builtin_amdgcn_exp2f(z[n][3]);
        pd[n * 2 + 0] = cvtpk(e0, e1);
        pd[n * 2 + 1] = cvtpk(e2, e3);
      }
      union U8 { uint32_t u[4]; bf8 v; } u0, u1;
      u0.u[0] = pd[0]; u0.u[1] = pd[1]; u0.u[2] = pd[2]; u0.u[3] = pd[3];
      u1.u[0] = pd[4]; u1.u[1] = pd[5]; u1.u[2] = pd[6]; u1.u[3] = pd[7];

      accL[qs] = __builtin_amdgcn_mfma_f32_16x16x32_bf16(u0.v, ones, accL[qs], 0, 0, 0);
      accL[qs] = __builtin_amdgcn_mfma_f32_16x16x32_bf16(u1.v, ones, accL[qs], 0, 0, 0);

#pragma unroll
      for (int dt = 0; dt < 4; ++dt) {
        o[qs][dt] = __builtin_amdgcn_mfma_f32_16x16x32_bf16(u0.v, vf[dt][0], o[qs][dt], 0, 0, 0);
        o[qs][dt] = __builtin_amdgcn_mfma_f32_16x16x32_bf16(u1.v, vf[dt][1], o[qs][dt], 0, 0, 0);
      }
    }

    __syncthreads();
    cur ^= 1;
  }
#undef STAGE

  const int b = bh >> 4, h = bh & 15;
#pragma unroll
  for (int qs = 0; qs < 2; ++qs)
#pragma unroll
    for (int j = 0; j < 4; ++j) {
      float invL = 1.0f / accL[qs][j];
      int q = q0 + qs * 16 + hi * 4 + j;
#pragma unroll
      for (int dt = 0; dt < 4; ++dt)
        O[(size_t)(b * T_ + q) * C_ + h * D_ + dt * 16 + lo] = f2bf(o[qs][dt][j] * invL);
    }
}

// ---------------------------------------------------------------- launch
extern "C" void kernel_launch(void* const* d_in, const int* in_sizes, int n_in,
                              void* d_out, int out_size, void* d_ws, size_t ws_size,
                              hipStream_t stream) {
  const float* x  = (const float*)d_in[0];
  // d_in[1] = mask: unused by the reference
  const float* qw = (const float*)d_in[2];
  const float* qb = (const float*)d_in[3];
  const float* kw = (const float*)d_in[4];
  const float* kb = (const float*)d_in[5];
  const float* vw = (const float*)d_in[6];
  const float* vb = (const float*)d_in[7];
  const float* ow = (const float*)d_in[8];
  const float* ob = (const float*)d_in[9];
  float* out = (float*)d_out;

  // workspace layout (88 MB). Q,K: [bh][t][d]; VT: [bh][d][t] (written directly
  // by the QKV GEMM -- no alias with xbf, which is live as A during that GEMM).
  char* ws = (char*)d_ws;
  ushort* xbf   = (ushort*)ws;                       // 16 MB
  ushort* qwbf  = (ushort*)(ws + (16u << 20));       // 2 MB each, contiguous (QKV stacked W)
  ushort* kwbf  = qwbf + (1u << 20);
  ushort* vwbf  = kwbf + (1u << 20);
  ushort* owbf  = vwbf + (1u << 20);
  ushort* Qws   = (ushort*)(ws + (24u << 20));       // Q @24MB, K @40MB, VT @56MB
  ushort* VTws  = (ushort*)(ws + (56u << 20));
  ushort* attnw = (ushort*)(ws + (72u << 20));

  hipFuncSetAttribute((const void*)gemm8, hipFuncAttributeMaxDynamicSharedMemorySize, 98304);

  // merged cast: x (8192 blocks) + 4 weights (4096 blocks)
  cast_all<<<12288, 256, 0, stream>>>(x, qw, kw, vw, ow, xbf, qwbf, kwbf, vwbf, owbf);

  const float QSC = 0.125f * 1.44269504f;  // 1/sqrt(D) * log2(e), folded into Q
  // fused QKV projection: N=3072 -> 12 n-tiles x 64 m-tiles = 768 blocks (3 full rounds)
  gemm8<<<768, 512, 98304, stream>>>(xbf, qwbf, qb, kb, vb, Qws, 1, QSC);

  attn_kernel<<<dim3(T_ / 128, B_ * H_), 256, 0, stream>>>(Qws, Qws + (size_t)(8u << 20), VTws, attnw);

  // final projection: N=1024 -> 4 n-tiles x 64 m-tiles = 256 blocks (1 full round)
  gemm8<<<256, 512, 98304, stream>>>(attnw, owbf, ob, nullptr, nullptr, out, 0, 1.0f);
}